// Round 2
// baseline (668.352 us; speedup 1.0000x reference)
//
#include <hip/hip_runtime.h>

// SpatialStyleModLayer fused kernel, round 2 (MI355X / gfx950)
//   mod  = style @ affine_w^T + affine_b + 1
//   out0 = (x * mod) @ W ;  ssq = (mod^2) @ (W^2) ;  out = out0*rsqrt(ssq+eps)+bias
// Structure change vs R1: weights pre-converted to bf16 ONCE (prep kernel into
// d_ws); main kernel loads all B-fragments global->reg (L2-resident), stages
// only style->LDS (one bulk pass), aliases mod over style (row-disjoint halves).
// Barriers per block: 33 -> 4. LDS 59KB -> 33.8KB.

#define CH   256
#define BM   64
#define EPS  1e-8f
#define P_M  264   // LDS pitch in shorts: 16B-aligned rows, bank step 4 (2-way, free)

typedef __attribute__((ext_vector_type(4))) float f32x4;
typedef __attribute__((ext_vector_type(8))) short bf16x8;
typedef __attribute__((ext_vector_type(4))) short s16x4;

__device__ __forceinline__ short f2b(float f) {          // f32 -> bf16 (RNE)
    union { float f; unsigned u; } v; v.f = f;
    unsigned r = v.u + 0x7fffu + ((v.u >> 16) & 1u);
    return (short)(r >> 16);
}
__device__ __forceinline__ float b2f(short b) {          // bf16 -> f32
    union { unsigned u; float f; } v;
    v.u = ((unsigned)(unsigned short)b) << 16;
    return v.f;
}

// One-time weight prep: wTb[o][i]=bf16(W[i][o]); wT2b[o][i]=bf16(bf16(W)^2);
// affwb[i][s]=bf16(affw[i][s]).  256 blocks x 256 threads, ~reads 512KB.
__global__ void prep_kernel(const float* __restrict__ weight,
                            const float* __restrict__ affw,
                            short* __restrict__ wTb, short* __restrict__ wT2b,
                            short* __restrict__ affwb)
{
    int t = threadIdx.x, b = blockIdx.x;
    float w  = weight[t * CH + b];
    short wb = f2b(w);
    float wf = b2f(wb);
    wTb [b * CH + t] = wb;
    wT2b[b * CH + t] = f2b(wf * wf);
    affwb[b * CH + t] = f2b(affw[b * CH + t]);
}

__global__ __launch_bounds__(256, 3)
void smod_main(const float* __restrict__ x, const float* __restrict__ style,
               const float* __restrict__ bias, const float* __restrict__ affb,
               const short* __restrict__ wTb, const short* __restrict__ wT2b,
               const short* __restrict__ affwb,
               float* __restrict__ out)
{
    __shared__ __align__(16) short tile[BM * P_M];       // style, then mod (aliased)

    const int tid  = threadIdx.x;
    const int lane = tid & 63;
    const int wid  = tid >> 6;          // 4 waves: wave owns 64 i's (ph1) / 64 o's (ph2)
    const int l15  = lane & 15;
    const int lgrp = lane >> 4;         // 0..3
    const int koff = lgrp << 3;         // k-offset within a K=32 MFMA step
    const long r0  = (long)blockIdx.x * BM;

    // ---- stage style tile [64][256] f32 -> bf16 LDS, one bulk coalesced pass ----
    #pragma unroll
    for (int k = 0; k < 16; ++k) {
        int f = (k << 8) + tid;                          // f32x4 index, 4096 total
        int r = f >> 6;
        int c = (f & 63) << 2;
        f32x4 v = *(const f32x4*)(style + (r0 + r) * CH + c);
        s16x4 o = { f2b(v[0]), f2b(v[1]), f2b(v[2]), f2b(v[3]) };
        *(s16x4*)(tile + r * P_M + c) = o;
    }
    __syncthreads();                                     // BAR 1

    // ---- Phase 1: mod^T = affwb * style^T, two row-halves (alias-safe) ----
    // half rh: MFMAs read style rows [rh*32, rh*32+32); mod writes same rows.
    #pragma unroll
    for (int rh = 0; rh < 2; ++rh) {
        f32x4 accm[4][2];
        #pragma unroll
        for (int a = 0; a < 4; ++a)
            #pragma unroll
            for (int b = 0; b < 2; ++b) { accm[a][b][0]=0.f; accm[a][b][1]=0.f; accm[a][b][2]=0.f; accm[a][b][3]=0.f; }

        #pragma unroll
        for (int kc = 0; kc < 8; ++kc) {
            bf16x8 a[4], b[2];
            #pragma unroll
            for (int it = 0; it < 4; ++it)
                a[it] = *(const bf16x8*)(affwb + (wid * 64 + it * 16 + l15) * CH + kc * 32 + koff);
            #pragma unroll
            for (int rt = 0; rt < 2; ++rt)
                b[rt] = *(const bf16x8*)(tile + (rh * 32 + rt * 16 + l15) * P_M + kc * 32 + koff);
            #pragma unroll
            for (int it = 0; it < 4; ++it)
                #pragma unroll
                for (int rt = 0; rt < 2; ++rt)
                    accm[it][rt] = __builtin_amdgcn_mfma_f32_16x16x32_bf16(
                        a[it], b[rt], accm[it][rt], 0, 0, 0);
        }
        __syncthreads();   // BAR 2 / BAR 3: all waves done reading this half's style rows

        // write mod (bf16) over this half's rows; next half reads disjoint rows
        #pragma unroll
        for (int it = 0; it < 4; ++it) {
            int ibase = wid * 64 + it * 16 + (lgrp << 2);
            f32x4 ab = *(const f32x4*)(affb + ibase);
            #pragma unroll
            for (int rt = 0; rt < 2; ++rt) {
                int row = rh * 32 + rt * 16 + l15;
                f32x4 m = accm[it][rt];
                s16x4 o = { f2b(m[0] + ab[0] + 1.0f), f2b(m[1] + ab[1] + 1.0f),
                            f2b(m[2] + ab[2] + 1.0f), f2b(m[3] + ab[3] + 1.0f) };
                *(s16x4*)(tile + row * P_M + ibase) = o;
            }
        }
    }
    __syncthreads();                                     // BAR 4: mod fully visible

    // ---- Phase 2: out0 / ssq GEMMs, zero barriers, W-frags global->reg ----
    #pragma unroll
    for (int rh = 0; rh < 2; ++rh) {
        f32x4 acc0[2][4], acc1[2][4];
        #pragma unroll
        for (int a = 0; a < 2; ++a)
            #pragma unroll
            for (int b = 0; b < 4; ++b) {
                acc0[a][b][0]=0.f; acc0[a][b][1]=0.f; acc0[a][b][2]=0.f; acc0[a][b][3]=0.f;
                acc1[a][b][0]=0.f; acc1[a][b][1]=0.f; acc1[a][b][2]=0.f; acc1[a][b][3]=0.f;
            }

        #pragma unroll
        for (int kc = 0; kc < 8; ++kc) {
            bf16x8 a1f[2], a2f[2];                       // x*mod and mod^2 frags
            #pragma unroll
            for (int rt = 0; rt < 2; ++rt) {
                int row = rh * 32 + rt * 16 + l15;
                bf16x8 mb = *(const bf16x8*)(tile + row * P_M + kc * 32 + koff);
                const float* xp = x + (r0 + row) * CH + kc * 32 + koff;
                f32x4 x0 = *(const f32x4*)xp;
                f32x4 x1 = *(const f32x4*)(xp + 4);
                #pragma unroll
                for (int j = 0; j < 8; ++j) {
                    float mf = b2f(mb[j]);
                    float xj = (j < 4) ? x0[j] : x1[j - 4];
                    a1f[rt][j] = f2b(mf * xj);
                    a2f[rt][j] = f2b(mf * mf);
                }
            }
            #pragma unroll
            for (int ct = 0; ct < 4; ++ct) {
                int o = wid * 64 + ct * 16 + l15;
                bf16x8 bw  = *(const bf16x8*)(wTb  + o * CH + kc * 32 + koff);
                bf16x8 bw2 = *(const bf16x8*)(wT2b + o * CH + kc * 32 + koff);
                #pragma unroll
                for (int rt = 0; rt < 2; ++rt) {
                    acc0[rt][ct] = __builtin_amdgcn_mfma_f32_16x16x32_bf16(
                        a1f[rt], bw,  acc0[rt][ct], 0, 0, 0);
                    acc1[rt][ct] = __builtin_amdgcn_mfma_f32_16x16x32_bf16(
                        a2f[rt], bw2, acc1[rt][ct], 0, 0, 0);
                }
            }
        }

        // epilogue for this half: demodulate + bias, coalesced f32 stores
        #pragma unroll
        for (int ct = 0; ct < 4; ++ct) {
            int o = wid * 64 + ct * 16 + l15;
            float bs = bias[o];
            #pragma unroll
            for (int rt = 0; rt < 2; ++rt) {
                int rowb = rh * 32 + rt * 16 + (lgrp << 2);
                #pragma unroll
                for (int r = 0; r < 4; ++r) {
                    float v = acc0[rt][ct][r] * rsqrtf(acc1[rt][ct][r] + EPS) + bs;
                    out[(r0 + rowb + r) * CH + o] = v;
                }
            }
        }
    }
}

extern "C" void kernel_launch(void* const* d_in, const int* in_sizes, int n_in,
                              void* d_out, int out_size, void* d_ws, size_t ws_size,
                              hipStream_t stream) {
    const float* x      = (const float*)d_in[0];
    const float* style  = (const float*)d_in[1];
    const float* weight = (const float*)d_in[2];
    const float* bias   = (const float*)d_in[3];
    const float* affw   = (const float*)d_in[4];
    const float* affb   = (const float*)d_in[5];
    float* outp = (float*)d_out;

    short* ws    = (short*)d_ws;
    short* wTb   = ws;                 // [256][256] bf16, 128 KB
    short* wT2b  = ws + CH * CH;       // [256][256] bf16, 128 KB
    short* affwb = ws + 2 * CH * CH;   // [256][256] bf16, 128 KB

    prep_kernel<<<dim3(CH), dim3(CH), 0, stream>>>(weight, affw, wTb, wT2b, affwb);

    const int rows = 4 * 65536;        // B*N = 262144
    smod_main<<<dim3(rows / BM), dim3(256), 0, stream>>>(
        x, style, bias, affb, wTb, wT2b, affwb, outp);
}

// Round 3
// 467.019 us; speedup vs baseline: 1.4311x; 1.4311x over previous
//
#include <hip/hip_runtime.h>

// SpatialStyleModLayer fused kernel, round 3 (MI355X / gfx950)
//   mod  = style @ affine_w^T + affine_b + 1
//   out0 = (x * mod) @ W ;  ssq = (mod^2) @ (W^2) ;  out = out0*rsqrt(ssq+eps)+bias
// R3 changes vs R2 (which was latency-serialized, VGPR=84, write-amplified):
//   1. x staged via global_load_lds DMA at block start -> HBM latency hidden under ph1
//   2. native __bf16 casts -> v_cvt_pk_bf16_f32 (4x less cvt VALU than manual RNE)
//   3. epilogue transposed through LDS (reuses dead x buffer) -> 1KB/wave coalesced
//      stores, kills the 1.85x WRITE_SIZE amplification
//   4. W loads issued at top of each unrolled kc body (counted waits cover L2 latency)

#define CH   256
#define BM   32
#define EPS  1e-8f
#define PT   264   // style/mod tile pitch (shorts): 16B-aligned rows, even bank spread
#define PX   260   // x/out buffer pitch (floats):   16B-aligned rows, even bank spread

typedef __attribute__((ext_vector_type(4))) float f32x4;
typedef __attribute__((ext_vector_type(8))) short bf16x8;
typedef __attribute__((ext_vector_type(4))) short s16x4;

__device__ __forceinline__ short f2b(float f) {          // f32 -> bf16 RNE via HW cvt
    __bf16 h = (__bf16)f;
    return __builtin_bit_cast(short, h);
}
__device__ __forceinline__ float b2f(short b) {          // bf16 -> f32 (1 shl)
    union { unsigned u; float f; } v;
    v.u = ((unsigned)(unsigned short)b) << 16;
    return v.f;
}
__device__ __forceinline__ void lds_dma16(const float* g, float* l) {
    // DMA 16B/lane global->LDS; LDS dest = uniform base + lane*16 (m104)
    __builtin_amdgcn_global_load_lds(
        (const __attribute__((address_space(1))) unsigned int*)g,
        (__attribute__((address_space(3))) unsigned int*)l, 16, 0, 0);
}

// One-time weight prep: wTb[o][i]=bf16(W[i][o]); wT2b[o][i]=bf16(bf16(W)^2);
// affwb[i][s]=bf16(affw[i][s]).
__global__ void prep_kernel(const float* __restrict__ weight,
                            const float* __restrict__ affw,
                            short* __restrict__ wTb, short* __restrict__ wT2b,
                            short* __restrict__ affwb)
{
    int t = threadIdx.x, b = blockIdx.x;
    float w  = weight[t * CH + b];
    short wb = f2b(w);
    float wf = b2f(wb);
    wTb  [b * CH + t] = wb;
    wT2b [b * CH + t] = f2b(wf * wf);
    affwb[b * CH + t] = f2b(affw[b * CH + t]);
}

__global__ __launch_bounds__(256, 2)
void smod_main(const float* __restrict__ x, const float* __restrict__ style,
               const float* __restrict__ bias, const float* __restrict__ affb,
               const short* __restrict__ wTb, const short* __restrict__ wT2b,
               const short* __restrict__ affwb,
               float* __restrict__ out)
{
    __shared__ __align__(16) short tile[BM * PT];        // style, then mod (16.9KB)
    __shared__ __align__(16) float xb[BM * PX];          // x (DMA), then out staging (33.3KB)

    const int tid  = threadIdx.x;
    const int lane = tid & 63;
    const int wid  = tid >> 6;          // 4 waves
    const int l15  = lane & 15;
    const int lgrp = lane >> 4;         // 0..3
    const int koff = lgrp << 3;
    const long r0  = (long)blockIdx.x * BM;

    // ---- x DMA: fire-and-forget, consumed in phase 2 (latency hidden by ph1) ----
    #pragma unroll
    for (int i = 0; i < 8; ++i) {
        int row = wid * 8 + i;
        lds_dma16(x + (r0 + row) * CH + lane * 4, &xb[row * PX]);
    }
    // ---- stage style [32][256] f32 -> bf16 LDS, coalesced 1KB/wave rows ----
    #pragma unroll
    for (int k = 0; k < 8; ++k) {
        int f = (k << 8) + tid;
        int r = f >> 6, c = (f & 63) << 2;
        f32x4 v = *(const f32x4*)(style + (r0 + r) * CH + c);
        s16x4 o = { f2b(v[0]), f2b(v[1]), f2b(v[2]), f2b(v[3]) };
        *(s16x4*)(tile + r * PT + c) = o;
    }
    __syncthreads();                                     // BAR 1: style visible

    // ---- Phase 1: mod^T = affwb @ style^T (wave owns 64 i's) ----
    f32x4 accm[4][2];
    #pragma unroll
    for (int a = 0; a < 4; ++a)
        #pragma unroll
        for (int b = 0; b < 2; ++b) { accm[a][b][0]=0.f; accm[a][b][1]=0.f; accm[a][b][2]=0.f; accm[a][b][3]=0.f; }

    #pragma unroll
    for (int kc = 0; kc < 8; ++kc) {
        bf16x8 a[4], b[2];
        #pragma unroll
        for (int it = 0; it < 4; ++it)
            a[it] = *(const bf16x8*)(affwb + (wid * 64 + it * 16 + l15) * CH + kc * 32 + koff);
        #pragma unroll
        for (int rt = 0; rt < 2; ++rt)
            b[rt] = *(const bf16x8*)(tile + (rt * 16 + l15) * PT + kc * 32 + koff);
        #pragma unroll
        for (int it = 0; it < 4; ++it)
            #pragma unroll
            for (int rt = 0; rt < 2; ++rt)
                accm[it][rt] = __builtin_amdgcn_mfma_f32_16x16x32_bf16(
                    a[it], b[rt], accm[it][rt], 0, 0, 0);
    }
    __syncthreads();                                     // BAR 2: style reads done

    // mod = acc + affb + 1 -> overwrite tile as [row][i] bf16 (b64 writes)
    #pragma unroll
    for (int it = 0; it < 4; ++it) {
        int ibase = wid * 64 + it * 16 + (lgrp << 2);
        f32x4 ab = *(const f32x4*)(affb + ibase);
        #pragma unroll
        for (int rt = 0; rt < 2; ++rt) {
            int row = rt * 16 + l15;
            f32x4 m = accm[it][rt];
            s16x4 o = { f2b(m[0] + ab[0] + 1.0f), f2b(m[1] + ab[1] + 1.0f),
                        f2b(m[2] + ab[2] + 1.0f), f2b(m[3] + ab[3] + 1.0f) };
            *(s16x4*)(tile + row * PT + ibase) = o;
        }
    }
    asm volatile("s_waitcnt vmcnt(0)" ::: "memory");     // drain own x-DMA
    __syncthreads();                                     // BAR 3: mod + all x visible

    // ---- Phase 2: out0/ssq GEMMs (wave owns 64 o's, 32 rows) ----
    f32x4 acc0[2][4], acc1[2][4];
    #pragma unroll
    for (int a = 0; a < 2; ++a)
        #pragma unroll
        for (int b = 0; b < 4; ++b) {
            acc0[a][b][0]=0.f; acc0[a][b][1]=0.f; acc0[a][b][2]=0.f; acc0[a][b][3]=0.f;
            acc1[a][b][0]=0.f; acc1[a][b][1]=0.f; acc1[a][b][2]=0.f; acc1[a][b][3]=0.f;
        }

    #pragma unroll
    for (int kc = 0; kc < 8; ++kc) {
        // W frags first: L2 latency covered by the prep VALU below (counted waits)
        bf16x8 bw[4], bw2[4];
        #pragma unroll
        for (int ct = 0; ct < 4; ++ct) {
            int o = wid * 64 + ct * 16 + l15;
            bw [ct] = *(const bf16x8*)(wTb  + o * CH + kc * 32 + koff);
            bw2[ct] = *(const bf16x8*)(wT2b + o * CH + kc * 32 + koff);
        }
        bf16x8 a1f[2], a2f[2];
        #pragma unroll
        for (int rt = 0; rt < 2; ++rt) {
            int row = rt * 16 + l15;
            bf16x8 mb = *(const bf16x8*)(tile + row * PT + kc * 32 + koff);
            f32x4 x0 = *(const f32x4*)(xb + row * PX + kc * 32 + koff);
            f32x4 x1 = *(const f32x4*)(xb + row * PX + kc * 32 + koff + 4);
            #pragma unroll
            for (int j = 0; j < 8; ++j) {
                float mf = b2f(mb[j]);
                float xj = (j < 4) ? x0[j] : x1[j - 4];
                a1f[rt][j] = f2b(mf * xj);
                a2f[rt][j] = f2b(mf * mf);
            }
        }
        #pragma unroll
        for (int ct = 0; ct < 4; ++ct)
            #pragma unroll
            for (int rt = 0; rt < 2; ++rt) {
                acc0[rt][ct] = __builtin_amdgcn_mfma_f32_16x16x32_bf16(
                    a1f[rt], bw[ct],  acc0[rt][ct], 0, 0, 0);
                acc1[rt][ct] = __builtin_amdgcn_mfma_f32_16x16x32_bf16(
                    a2f[rt], bw2[ct], acc1[rt][ct], 0, 0, 0);
            }
    }
    __syncthreads();                                     // BAR 4: x reads done

    // ---- Epilogue: demod+bias -> xb (as f32 [32][PX]), then coalesced stores ----
    #pragma unroll
    for (int ct = 0; ct < 4; ++ct) {
        int o = wid * 64 + ct * 16 + l15;
        float bs = bias[o];
        #pragma unroll
        for (int rt = 0; rt < 2; ++rt)
            #pragma unroll
            for (int r = 0; r < 4; ++r) {
                int row = rt * 16 + (lgrp << 2) + r;
                xb[row * PX + o] = acc0[rt][ct][r] * rsqrtf(acc1[rt][ct][r] + EPS) + bs;
            }
    }
    __syncthreads();                                     // BAR 5: out tile visible

    #pragma unroll
    for (int k = 0; k < 8; ++k) {
        int f = (k << 8) + tid;
        int row = f >> 6, c = (f & 63) << 2;             // 32 rows x 64 chunks
        f32x4 v = *(const f32x4*)(xb + row * PX + c);
        *(f32x4*)(out + (r0 + row) * CH + c) = v;        // 1KB/wave contiguous
    }
}

extern "C" void kernel_launch(void* const* d_in, const int* in_sizes, int n_in,
                              void* d_out, int out_size, void* d_ws, size_t ws_size,
                              hipStream_t stream) {
    const float* x      = (const float*)d_in[0];
    const float* style  = (const float*)d_in[1];
    const float* weight = (const float*)d_in[2];
    const float* bias   = (const float*)d_in[3];
    const float* affw   = (const float*)d_in[4];
    const float* affb   = (const float*)d_in[5];
    float* outp = (float*)d_out;

    short* ws    = (short*)d_ws;
    short* wTb   = ws;                 // [256][256] bf16
    short* wT2b  = ws + CH * CH;
    short* affwb = ws + 2 * CH * CH;

    prep_kernel<<<dim3(CH), dim3(CH), 0, stream>>>(weight, affw, wTb, wT2b, affwb);

    const int rows = 4 * 65536;        // 262144
    smod_main<<<dim3(rows / BM), dim3(256), 0, stream>>>(
        x, style, bias, affb, wTb, wT2b, affwb, outp);
}

// Round 4
// 284.003 us; speedup vs baseline: 2.3533x; 1.6444x over previous
//
#include <hip/hip_runtime.h>

// SpatialStyleModLayer fused kernel, round 4 (MI355X / gfx950)
//   mod  = style @ affine_w^T + affine_b + 1
//   out0 = (x * mod) @ W ;  ssq = (mod^2) @ (W^2) ;  out = out0*rsqrt(ssq+eps)+bias
// R4 vs R3 (which was latency-bound: MfmaUtil 8%, 1.1 TB/s, blocks stalled 10x):
//   - BM=64, 8 waves/512thr, 4096 blocks: W-table L2 traffic halved per row
//   - bulk up-front reg-staged loads (16 dwordx4/thread in flight) for MLP
//   - a-prep pass computes a1=bf16(x*mod), a2=bf16(mod^2) ONCE into LDS
//     (x stays f32 in regs -> no extra rounding); phase-2 loop is pure MFMA+loads
//   - XOR-swizzled LDS (T2), conflict-free b128; 64KB static -> 2 blocks/CU
//   - __launch_bounds__(512,4) caps VGPR at 128 (design peak ~110)

#define CH   256
#define BM   64
#define EPS  1e-8f

typedef __attribute__((ext_vector_type(4))) float f32x4;
typedef __attribute__((ext_vector_type(8))) short bf16x8;
typedef __attribute__((ext_vector_type(4))) short s16x4;

__device__ __forceinline__ short f2b(float f) {          // f32 -> bf16 RNE (HW cvt)
    __bf16 h = (__bf16)f;
    return __builtin_bit_cast(short, h);
}
__device__ __forceinline__ float b2f(short b) {
    union { unsigned u; float f; } v;
    v.u = ((unsigned)(unsigned short)b) << 16;
    return v.f;
}
// Swizzled byte offset into a 64-row x 512B-row bf16 tile. chunk = 16B unit.
__device__ __forceinline__ int swz(int row, int chunk) {
    return row * 512 + ((chunk ^ (row & 7)) << 4);
}

// One-time weight prep: wTb[o][i]=bf16(W[i][o]); wT2b[o][i]=bf16(bf16(W)^2);
// affwb[i][s]=bf16(affw[i][s]).
__global__ void prep_kernel(const float* __restrict__ weight,
                            const float* __restrict__ affw,
                            short* __restrict__ wTb, short* __restrict__ wT2b,
                            short* __restrict__ affwb)
{
    int t = threadIdx.x, b = blockIdx.x;
    float w  = weight[t * CH + b];
    short wb = f2b(w);
    float wf = b2f(wb);
    wTb  [b * CH + t] = wb;
    wT2b [b * CH + t] = f2b(wf * wf);
    affwb[b * CH + t] = f2b(affw[b * CH + t]);
}

__global__ __launch_bounds__(512, 4)
void smod_main(const float* __restrict__ x, const float* __restrict__ style,
               const float* __restrict__ bias, const float* __restrict__ affb,
               const short* __restrict__ wTb, const short* __restrict__ wT2b,
               const short* __restrict__ affwb,
               float* __restrict__ out)
{
    __shared__ __align__(16) unsigned char smem[65536];  // exactly 64 KB
    char* regA = (char*)smem;            // style -> a1   (32 KB)
    char* regB = (char*)smem + 32768;    // mod   -> a2   (32 KB)

    const int tid  = threadIdx.x;
    const int lane = tid & 63;
    const int wid  = tid >> 6;           // 0..7
    const int l15  = lane & 15;
    const int lgrp = lane >> 4;          // 0..3
    const int koff = lgrp << 3;          // bf16 elems within K=32 step
    const long r0  = (long)blockIdx.x * BM;

    // unit mapping for staging / a-prep: unit = (row = k*16 + wid*2 + (lane>>5),
    // ch8 = lane&31); one unit = one 16B LDS chunk = 8 elements.
    const int urow = (wid << 1) + (lane >> 5);
    const int uch  = lane & 31;

    // ---- issue style loads (2 dwordx4 per unit; wave reads 2 contiguous rows) ----
    f32x4 sld[4][2];
    #pragma unroll
    for (int k = 0; k < 4; ++k) {
        const float* p = style + (r0 + k * 16 + urow) * CH + uch * 8;
        sld[k][0] = *(const f32x4*)p;
        sld[k][1] = *(const f32x4*)(p + 4);
    }
    // ---- issue x loads (consumed after phase 1, in a-prep; stays f32) ----
    f32x4 xld[4][2];
    #pragma unroll
    for (int k = 0; k < 4; ++k) {
        const float* p = x + (r0 + k * 16 + urow) * CH + uch * 8;
        xld[k][0] = *(const f32x4*)p;
        xld[k][1] = *(const f32x4*)(p + 4);
    }
    // ---- cvt style -> regA (swizzled b128 writes, conflict-free) ----
    #pragma unroll
    for (int k = 0; k < 4; ++k) {
        int row = k * 16 + urow;
        bf16x8 v;
        #pragma unroll
        for (int j = 0; j < 8; ++j)
            v[j] = f2b(j < 4 ? sld[k][0][j] : sld[k][1][j - 4]);
        *(bf16x8*)(regA + swz(row, uch)) = v;
    }
    __syncthreads();                                     // BAR 1: style visible

    // ---- Phase 1: mod^T = affwb @ style^T. Wave owns 32 i's (it=0..1). ----
    f32x4 accm[2][4];
    #pragma unroll
    for (int a = 0; a < 2; ++a)
        #pragma unroll
        for (int b = 0; b < 4; ++b) { accm[a][b][0]=0.f; accm[a][b][1]=0.f; accm[a][b][2]=0.f; accm[a][b][3]=0.f; }

    #pragma unroll
    for (int kc = 0; kc < 8; ++kc) {
        bf16x8 af[2];
        #pragma unroll
        for (int it = 0; it < 2; ++it)
            af[it] = *(const bf16x8*)(affwb + (wid * 32 + it * 16 + l15) * CH + kc * 32 + koff);
        #pragma unroll
        for (int rt = 0; rt < 4; ++rt) {
            bf16x8 bfr = *(const bf16x8*)(regA + swz(rt * 16 + l15, kc * 4 + lgrp));
            #pragma unroll
            for (int it = 0; it < 2; ++it)
                accm[it][rt] = __builtin_amdgcn_mfma_f32_16x16x32_bf16(
                    af[it], bfr, accm[it][rt], 0, 0, 0);
        }
    }

    // mod = accm + affb + 1 -> regB (b64 scatter; C-frag m gives 4 consecutive i)
    #pragma unroll
    for (int it = 0; it < 2; ++it) {
        int i0 = wid * 32 + it * 16 + (lgrp << 2);
        f32x4 ab = *(const f32x4*)(affb + i0);
        int chunk = i0 >> 3;
        int sub   = (i0 & 7) << 1;                       // byte offset in chunk
        #pragma unroll
        for (int rt = 0; rt < 4; ++rt) {
            int row = rt * 16 + l15;
            f32x4 m = accm[it][rt];
            s16x4 o4 = { f2b(m[0] + ab[0] + 1.0f), f2b(m[1] + ab[1] + 1.0f),
                         f2b(m[2] + ab[2] + 1.0f), f2b(m[3] + ab[3] + 1.0f) };
            *(s16x4*)(regB + swz(row, chunk) + sub) = o4;
        }
    }
    __syncthreads();      // BAR 2: mod complete; style reads complete

    // ---- a-prep: a1 = bf16(x_f32 * mod), a2 = bf16(mod^2), ONCE per element ----
    #pragma unroll
    for (int k = 0; k < 4; ++k) {
        int row = k * 16 + urow;
        bf16x8 mb = *(const bf16x8*)(regB + swz(row, uch));
        bf16x8 a1v, a2v;
        #pragma unroll
        for (int j = 0; j < 8; ++j) {
            float mf = b2f(mb[j]);
            float xf = (j < 4) ? xld[k][0][j] : xld[k][1][j - 4];
            a1v[j] = f2b(xf * mf);
            a2v[j] = f2b(mf * mf);
        }
        *(bf16x8*)(regA + swz(row, uch)) = a1v;          // over dead style
        *(bf16x8*)(regB + swz(row, uch)) = a2v;          // in-place over mod
    }
    __syncthreads();                                     // BAR 3: a1/a2 visible

    // ---- Phase 2: out0 = a1 @ W^T, ssq = a2 @ (W^2)^T. Wave owns 32 o's. ----
    f32x4 acc0[4][2], acc1[4][2];
    #pragma unroll
    for (int a = 0; a < 4; ++a)
        #pragma unroll
        for (int b = 0; b < 2; ++b) {
            acc0[a][b][0]=0.f; acc0[a][b][1]=0.f; acc0[a][b][2]=0.f; acc0[a][b][3]=0.f;
            acc1[a][b][0]=0.f; acc1[a][b][1]=0.f; acc1[a][b][2]=0.f; acc1[a][b][3]=0.f;
        }

    #pragma unroll
    for (int kc = 0; kc < 8; ++kc) {
        bf16x8 bw[2], bw2[2];
        #pragma unroll
        for (int ct = 0; ct < 2; ++ct) {
            int o = wid * 32 + ct * 16 + l15;
            bw [ct] = *(const bf16x8*)(wTb  + o * CH + kc * 32 + koff);
            bw2[ct] = *(const bf16x8*)(wT2b + o * CH + kc * 32 + koff);
        }
        #pragma unroll
        for (int rt = 0; rt < 4; ++rt) {
            int row = rt * 16 + l15;
            bf16x8 a1f = *(const bf16x8*)(regA + swz(row, kc * 4 + lgrp));
            bf16x8 a2f = *(const bf16x8*)(regB + swz(row, kc * 4 + lgrp));
            #pragma unroll
            for (int ct = 0; ct < 2; ++ct) {
                acc0[rt][ct] = __builtin_amdgcn_mfma_f32_16x16x32_bf16(
                    a1f, bw[ct],  acc0[rt][ct], 0, 0, 0);
                acc1[rt][ct] = __builtin_amdgcn_mfma_f32_16x16x32_bf16(
                    a2f, bw2[ct], acc1[rt][ct], 0, 0, 0);
            }
        }
    }
    __syncthreads();                                     // BAR 4: LDS reads done

    // ---- Epilogue: demod + bias -> swizzled f32 tile (64 x 1024B over smem) ----
    #pragma unroll
    for (int ct = 0; ct < 2; ++ct) {
        int o = wid * 32 + ct * 16 + l15;
        float bs = bias[o];
        int cO = o >> 2, sub = (o & 3) << 2;
        #pragma unroll
        for (int rt = 0; rt < 4; ++rt)
            #pragma unroll
            for (int j = 0; j < 4; ++j) {
                int row = rt * 16 + (lgrp << 2) + j;
                float v = acc0[rt][ct][j] * rsqrtf(acc1[rt][ct][j] + EPS) + bs;
                *(float*)((char*)smem + row * 1024 + (((cO ^ (row & 7)) << 4)) + sub) = v;
            }
    }
    __syncthreads();                                     // BAR 5: tile visible

    // ---- coalesced stores: one full 1KB row per wave-instruction ----
    #pragma unroll
    for (int k = 0; k < 8; ++k) {
        int row = (k << 3) + wid;
        f32x4 v = *(const f32x4*)((char*)smem + row * 1024 + ((lane ^ (row & 7)) << 4));
        *(f32x4*)(out + (r0 + row) * CH + (lane << 2)) = v;
    }
}

extern "C" void kernel_launch(void* const* d_in, const int* in_sizes, int n_in,
                              void* d_out, int out_size, void* d_ws, size_t ws_size,
                              hipStream_t stream) {
    const float* x      = (const float*)d_in[0];
    const float* style  = (const float*)d_in[1];
    const float* weight = (const float*)d_in[2];
    const float* bias   = (const float*)d_in[3];
    const float* affw   = (const float*)d_in[4];
    const float* affb   = (const float*)d_in[5];
    float* outp = (float*)d_out;

    short* ws    = (short*)d_ws;
    short* wTb   = ws;                 // [256][256] bf16
    short* wT2b  = ws + CH * CH;
    short* affwb = ws + 2 * CH * CH;

    prep_kernel<<<dim3(CH), dim3(CH), 0, stream>>>(weight, affw, wTb, wT2b, affwb);

    const int rows = 4 * 65536;        // 262144
    smod_main<<<dim3(rows / BM), dim3(512), 0, stream>>>(
        x, style, bias, affb, wTb, wT2b, affwb, outp);
}